// Round 1
// baseline (103.149 us; speedup 1.0000x reference)
//
#include <hip/hip_runtime.h>

// IndRNN net, algebraically collapsed (verified exact, absmax=0.0 in R1-R4):
// predict uses only decoder-batch 0 => last[0] = y_enc1[t=0, b=4095] =>
// encoder needed only at (t=0, b=4095); recurrent u terms vanish at t=0.
// 3-kernel chain (R2: in-kernel grid barriers cost ~60us/barrier cross-XCD;
// R3: ~90us harness floor = 268MB ws poison fill ~42us + input restores).
// R5: kernels are latency-bound, not BW-bound. Remove the LDS-staging
// barriers in K1/K2 (each lane recomputes / directly loads the 16 vector
// elements its dot needs) so ALL global loads issue at wave start — one
// HBM latency exposure instead of two serialized ones. K3: explicitly
// hoist all 20 G float4 loads above the reduce chains.

#define HID 1024
#define TSTEPS 20

__device__ __forceinline__ float wred64(float v) {
#pragma unroll
    for (int off = 32; off > 0; off >>= 1) v += __shfl_down(v, off, 64);
    return v;  // lane 0 holds the sum
}

// K1: last0[r] = relu(ew1[r] @ relu(ew0 @ x[0,4095] + eb0) + eb1[r])
// Barrier-free: v0[j] = relu(ew0[j]*x + eb0[j]) depends only on j, so each
// lane computes the 16 v0 elements its ew1-row chunk needs directly from the
// 8KB ew0 (L2-broadcast across blocks). No LDS, no __syncthreads => the
// 16KB/row ew1 loads issue immediately at wave start.
// Also seeds out[t][j] = ob[j] (K3 accumulates via atomicAdd; stream order
// K1 -> K3 guarantees the seed lands first).
__global__ __launch_bounds__(256, 1) void k_enc(
    const float* __restrict__ x, const float* __restrict__ ew0,
    const float* __restrict__ eb0, const float* __restrict__ ew1,
    const float* __restrict__ eb1, const float* __restrict__ ob,
    float* __restrict__ last0, float* __restrict__ out) {
    const int tid = threadIdx.x, wave = tid >> 6, lane = tid & 63;

    if (blockIdx.x == 0 && tid < 2 * TSTEPS) out[tid] = ob[tid & 1];

    const float x0 = x[8190], x1 = x[8191];  // x[t=0, b=4095, :]
    const int r = blockIdx.x * 4 + wave;     // wave per output row
    const float4* __restrict__ wrow = (const float4*)(ew1 + r * HID);
    const float4* __restrict__ w0p = (const float4*)ew0;  // 2 rows per float4
    const float4* __restrict__ b0p = (const float4*)eb0;
    float s = 0.f;
#pragma unroll
    for (int k = 0; k < 4; ++k) {
        const int j = k * 64 + lane;         // float4 index: v0[4j..4j+3]
        float4 w  = wrow[j];                 // ew1 row r, cols 4j..4j+3
        float4 wa = w0p[2 * j];              // ew0 rows 4j, 4j+1
        float4 wb = w0p[2 * j + 1];          // ew0 rows 4j+2, 4j+3
        float4 e  = b0p[j];                  // eb0[4j..4j+3]
        // identical fma order to the R4 kernel => bit-identical v0
        float v0 = fmaxf(fmaf(wa.x, x0, fmaf(wa.y, x1, e.x)), 0.f);
        float v1 = fmaxf(fmaf(wa.z, x0, fmaf(wa.w, x1, e.y)), 0.f);
        float v2 = fmaxf(fmaf(wb.x, x0, fmaf(wb.y, x1, e.z)), 0.f);
        float v3 = fmaxf(fmaf(wb.z, x0, fmaf(wb.w, x1, e.w)), 0.f);
        s = fmaf(w.x, v0, s); s = fmaf(w.y, v1, s);
        s = fmaf(w.z, v2, s); s = fmaf(w.w, v3, s);
    }
    s = wred64(s);
    if (lane == 0) last0[r] = fmaxf(s + eb1[r], 0.f);
}

// K2: p = dw0 @ last0 + db0; G[t][h] = scan relu(p + u0*g)
// Barrier-free: last0 is 4KB; each lane loads its own float4 slice directly
// from global (LLC-resident) instead of staging through LDS. dw0 row loads
// issue concurrently at wave start.
__global__ __launch_bounds__(256, 1) void k_dec0(
    const float* __restrict__ last0, const float* __restrict__ dw0,
    const float* __restrict__ du0, const float* __restrict__ db0,
    float* __restrict__ G) {
    const int tid = threadIdx.x, wave = tid >> 6, lane = tid & 63;
    const int r = blockIdx.x * 4 + wave;
    const float4* __restrict__ wrow = (const float4*)(dw0 + r * HID);
    const float4* __restrict__ v4 = (const float4*)last0;
    float s = 0.f;
#pragma unroll
    for (int k = 0; k < 4; ++k) {
        float4 w = wrow[k * 64 + lane], v = v4[k * 64 + lane];
        s = fmaf(w.x, v.x, s); s = fmaf(w.y, v.y, s);
        s = fmaf(w.z, v.z, s); s = fmaf(w.w, v.w, s);
    }
    s = wred64(s);
    if (lane == 0) {
        const float p = s + db0[r], uu = du0[r];
        float g = 0.f;
#pragma unroll
        for (int t = 0; t < TSTEPS; ++t) {
            g = fmaxf(fmaf(uu, g, p), 0.f);
            G[t * HID + r] = g;
        }
    }
}

// K3: Q[t] = dw1 @ G[t] + db1; H1[t] = scan relu(q + u1*h);
// out[t][j] += ow[j] . H1[t]  (per-block partials + atomicAdd).
// 256 blocks x 4 rows; 20 independent reductions split across 4 waves
// (wave w does t = w, w+4..w+16). All 16 w-float4s AND all 20 g-float4s
// are loaded before the reduce chains (~150 live VGPRs; launch_bounds(,1)
// keeps the allocator from capping registers — 1 block/CU anyway).
__global__ __launch_bounds__(256, 1) void k_dec1_out(
    const float* __restrict__ G, const float* __restrict__ dw1,
    const float* __restrict__ du1, const float* __restrict__ db1,
    const float* __restrict__ ow, float* __restrict__ out) {
    const int tid = threadIdx.x, wave = tid >> 6, lane = tid & 63;
    const int r0 = blockIdx.x * 4;
    __shared__ float qs[TSTEPS][4];   // Q[t][row]
    __shared__ float hs[TSTEPS][4];   // H1[t][row]

    // every wave holds all 4 rows' weight chunks (16 KB/block, L1-shared)
    float4 w[4][4];
#pragma unroll
    for (int r = 0; r < 4; ++r) {
        const float4* wr = (const float4*)(dw1 + (r0 + r) * HID);
#pragma unroll
        for (int k = 0; k < 4; ++k) w[r][k] = wr[k * 64 + lane];
    }
    // hoist all 5 rounds' G slices: issue every global load up front
    float4 g[5][4];
#pragma unroll
    for (int ti = 0; ti < 5; ++ti) {
        const float4* gt = (const float4*)(G + (wave + ti * 4) * HID);
#pragma unroll
        for (int k = 0; k < 4; ++k) g[ti][k] = gt[k * 64 + lane];
    }

#pragma unroll
    for (int ti = 0; ti < 5; ++ti) {
        const int t = wave + ti * 4;
        float s[4] = {0.f, 0.f, 0.f, 0.f};
#pragma unroll
        for (int r = 0; r < 4; ++r)
#pragma unroll
            for (int k = 0; k < 4; ++k) {
                s[r] = fmaf(w[r][k].x, g[ti][k].x, s[r]);
                s[r] = fmaf(w[r][k].y, g[ti][k].y, s[r]);
                s[r] = fmaf(w[r][k].z, g[ti][k].z, s[r]);
                s[r] = fmaf(w[r][k].w, g[ti][k].w, s[r]);
            }
#pragma unroll
        for (int off = 32; off > 0; off >>= 1) {
            s[0] += __shfl_down(s[0], off, 64);
            s[1] += __shfl_down(s[1], off, 64);
            s[2] += __shfl_down(s[2], off, 64);
            s[3] += __shfl_down(s[3], off, 64);
        }
        if (lane == 0) {
            qs[t][0] = s[0]; qs[t][1] = s[1];
            qs[t][2] = s[2]; qs[t][3] = s[3];
        }
    }
    __syncthreads();

    if (tid < 4) {                       // 20-step scan per row (serial, tiny)
        const int r = r0 + tid;
        const float uu = du1[r], bb = db1[r];
        float h = 0.f;
#pragma unroll
        for (int t = 0; t < TSTEPS; ++t) {
            h = fmaxf(fmaf(uu, h, qs[t][tid] + bb), 0.f);
            hs[t][tid] = h;
        }
    }
    __syncthreads();

    if (tid < 2 * TSTEPS) {              // output partials: 40 threads
        const int t = tid >> 1, j = tid & 1;
        const float* owj = ow + j * HID + r0;
        float p = owj[0] * hs[t][0] + owj[1] * hs[t][1]
                + owj[2] * hs[t][2] + owj[3] * hs[t][3];
        atomicAdd(&out[t * 2 + j], p);
    }
}

extern "C" void kernel_launch(void* const* d_in, const int* in_sizes, int n_in,
                              void* d_out, int out_size, void* d_ws, size_t ws_size,
                              hipStream_t stream) {
    const float* x      = (const float*)d_in[0];
    const float* enc_w0 = (const float*)d_in[1];
    // d_in[2] = enc_u0 — provably unused (encoder only matters at t=0)
    const float* enc_b0 = (const float*)d_in[3];
    const float* enc_w1 = (const float*)d_in[4];
    // d_in[5] = enc_u1 — unused
    const float* enc_b1 = (const float*)d_in[6];
    const float* dec_w0 = (const float*)d_in[7];
    const float* dec_u0 = (const float*)d_in[8];
    const float* dec_b0 = (const float*)d_in[9];
    const float* dec_w1 = (const float*)d_in[10];
    const float* dec_u1 = (const float*)d_in[11];
    const float* dec_b1 = (const float*)d_in[12];
    const float* out_w  = (const float*)d_in[13];
    const float* out_b  = (const float*)d_in[14];
    float* out = (float*)d_out;

    float* ws    = (float*)d_ws;
    float* last0 = ws;          // 1024 floats
    float* G     = ws + HID;    // 20*1024 floats

    k_enc<<<256, 256, 0, stream>>>(x, enc_w0, enc_b0, enc_w1, enc_b1,
                                   out_b, last0, out);
    k_dec0<<<256, 256, 0, stream>>>(last0, dec_w0, dec_u0, dec_b0, G);
    k_dec1_out<<<256, 256, 0, stream>>>(G, dec_w1, dec_u1, dec_b1, out_w, out);
}